// Round 11
// baseline (16364.238 us; speedup 1.0000x reference)
//
#include <hip/hip_runtime.h>
#include <hip/hip_bf16.h>

#define B_ 64
#define T_ 1024
#define D_ 512
#define H_ 512
#define O_ 512
#define NBLK 32        // j-slice blocks in recurrent kernel
#define FSTR 32        // flag stride in u32 (one 128-B line per flag)

using bf16x8 = __attribute__((ext_vector_type(8))) short;
using f32x4  = __attribute__((ext_vector_type(4))) float;

__device__ __forceinline__ short f2bfs(float f) {
  return (short)__builtin_bit_cast(unsigned short, __float2bfloat16(f));
}
__device__ __forceinline__ float sigmoid_f(float v) {
  return 1.0f / (1.0f + __expf(-v));
}
__device__ __forceinline__ float tanh_f(float v) {
  float a = fabsf(v);
  float e = __expf(-2.0f * a);
  float t = (1.0f - e) / (1.0f + e);
  return copysignf(t, v);
}

// ---------------------------------------------------------------------------
// Setup: pack W_all (1024x2048) and W_hy (512x512) into MFMA B-fragment order
// (bf16), convert h_init to bf16 (standard (B,H) layout), zero strided flags.
// ---------------------------------------------------------------------------
__global__ __launch_bounds__(256) void pack_setup(
    const float* __restrict__ Wf, const float* __restrict__ Wi,
    const float* __restrict__ Wc, const float* __restrict__ Wo,
    const float* __restrict__ Why, const float* __restrict__ hinit,
    unsigned short* __restrict__ Wp, unsigned short* __restrict__ Whyp,
    unsigned short* __restrict__ hbf0, unsigned int* __restrict__ flg)
{
  long idx = (long)blockIdx.x * blockDim.x + threadIdx.x;
  if (idx < NBLK * FSTR) flg[idx] = 0u;        // re-zeroed every call
  const long NW = 1024L * 2048;
  const long NY = 512L * 512;
  const long NH = 64L * 512;
  if (idx < NW) {
    int e = idx & 7, l = (idx >> 3) & 63, kk = (idx >> 9) & 31;
    int Jc = (int)(idx >> 14);                   // 0..127
    int k = kk * 32 + (l >> 4) * 8 + e;          // 0..1023
    int col = Jc * 16 + (l & 15);                // 0..2047
    int gg = col >> 9, j = col & 511;
    const float* W = (gg == 0) ? Wf : (gg == 1) ? Wi : (gg == 2) ? Wc : Wo;
    Wp[idx] = (unsigned short)f2bfs(W[(long)k * 512 + j]);
  } else if (idx < NW + NY) {
    long q = idx - NW;
    int e = q & 7, l = (q >> 3) & 63, kk = (q >> 9) & 15;
    int J = (int)(q >> 13);
    int k = kk * 32 + (l >> 4) * 8 + e;
    int col = J * 16 + (l & 15);
    Whyp[q] = (unsigned short)f2bfs(Why[(long)k * 512 + col]);
  } else if (idx < NW + NY + NH) {
    long q = idx - NW - NY;
    hbf0[q] = (unsigned short)f2bfs(hinit[q]);
  }
}

// ---------------------------------------------------------------------------
// x fp32 -> bf16 streaming conversion.
// ---------------------------------------------------------------------------
__global__ __launch_bounds__(256) void xconv(
    const float* __restrict__ x, unsigned short* __restrict__ xb)
{
  long i = ((long)blockIdx.x * 256 + threadIdx.x) * 8;
  float4 a = *(const float4*)(x + i);
  float4 b = *(const float4*)(x + i + 4);
  bf16x8 v;
  v[0] = f2bfs(a.x); v[1] = f2bfs(a.y); v[2] = f2bfs(a.z); v[3] = f2bfs(a.w);
  v[4] = f2bfs(b.x); v[5] = f2bfs(b.y); v[6] = f2bfs(b.z); v[7] = f2bfs(b.w);
  *(bf16x8*)(xb + i) = v;
}

// ---------------------------------------------------------------------------
// Sequential recurrence (R4-proven data path + EAGER L2 WRITEBACK publish).
// 32 blocks x 256 threads. Per step:
//   x-half MFMAs -> wave0 sc1-poll of 32 private flag lines -> h loads
//   (agent u64, L3-fresh) -> h-half MFMAs -> gates -> h stored with PLAIN
//   cached stores -> __syncthreads -> wave0: buffer_wbl2 sc1 (flush dirty
//   L2 to L3, vmcnt-tracked) -> flag published via atomicExchange (executes
//   at coherence point, immune to write-through buffering).
// Flag >= t+1  =>  wbl2 done  =>  h_t in L3  =>  consumer sc1 reads fresh.
// ---------------------------------------------------------------------------
template<bool X16>
__global__ __launch_bounds__(256, 1) void lstm_seq(
    const void* __restrict__ xv,      // (B,T,D) bf16 or fp32
    const float* __restrict__ cinit,  // (B,H)
    const float* __restrict__ bf_, const float* __restrict__ bi_,
    const float* __restrict__ bc_, const float* __restrict__ bo_,
    const unsigned short* __restrict__ Wp,
    unsigned short* __restrict__ hbf0,
    unsigned short* __restrict__ hbf1,
    unsigned short* __restrict__ hs,  // (T,B,H) bf16
    float* __restrict__ tail,         // d_out + B*T*O : h_fin then c_fin
    unsigned int* __restrict__ flg)
{
  const int jb   = blockIdx.x;
  const int tid  = threadIdx.x;
  const int wv   = tid >> 6;
  const int lane = tid & 63;
  const int lrow = lane & 15;
  const int lkg  = lane >> 4;
  const int b_arow = wv * 16 + lrow;
  const int jcol   = jb * 16 + lrow;
  const int b_cd0  = wv * 16 + lkg * 4;

  const float vbf = bf_[jcol], vbi = bi_[jcol], vbc = bc_[jcol], vbo = bo_[jcol];
  float c0 = cinit[(long)(b_cd0 + 0) * H_ + jcol];
  float c1 = cinit[(long)(b_cd0 + 1) * H_ + jcol];
  float c2 = cinit[(long)(b_cd0 + 2) * H_ + jcol];
  float c3 = cinit[(long)(b_cd0 + 3) * H_ + jcol];

  const long aq = (long)b_arow * 128 + lkg * 2;   // u64 index into h buffers
  const unsigned short* xrow16 = X16 ? (const unsigned short*)xv + (long)b_arow * T_ * D_ + lkg * 8 : nullptr;
  const float*          xrow32 = X16 ? nullptr : (const float*)xv + (long)b_arow * T_ * D_ + lkg * 8;
  const unsigned short* w0 = Wp + (long)(0 * 32 + jb) * 32 * 512 + lane * 8;
  const unsigned short* w1 = Wp + (long)(1 * 32 + jb) * 32 * 512 + lane * 8;
  const unsigned short* w2 = Wp + (long)(2 * 32 + jb) * 32 * 512 + lane * 8;
  const unsigned short* w3 = Wp + (long)(3 * 32 + jb) * 32 * 512 + lane * 8;
  const unsigned long long* h0q = (const unsigned long long*)hbf0;
  const unsigned long long* h1q = (const unsigned long long*)hbf1;

  bf16x8 xf[16];
  float4 xr[32];
  if constexpr (X16) {
    #pragma unroll
    for (int kk = 0; kk < 16; ++kk) xf[kk] = *(const bf16x8*)(xrow16 + kk * 32);
  } else {
    #pragma unroll
    for (int kk = 0; kk < 16; ++kk) {
      xr[2*kk]   = *(const float4*)(xrow32 + kk * 32);
      xr[2*kk+1] = *(const float4*)(xrow32 + kk * 32 + 4);
    }
  }

  #pragma unroll 1
  for (int t = 0; t < T_; ++t) {
    // ---- x half of GEMM (k 512..1023) before the poll ----
    f32x4 af = {vbf, vbf, vbf, vbf};
    f32x4 ai = {vbi, vbi, vbi, vbi};
    f32x4 ac = {vbc, vbc, vbc, vbc};
    f32x4 ao = {vbo, vbo, vbo, vbo};
    #pragma unroll
    for (int kk = 0; kk < 16; ++kk) {
      bf16x8 ax;
      if constexpr (X16) {
        ax = xf[kk];
      } else {
        float4 xa = xr[2*kk], xb2 = xr[2*kk+1];
        ax[0]=f2bfs(xa.x); ax[1]=f2bfs(xa.y); ax[2]=f2bfs(xa.z); ax[3]=f2bfs(xa.w);
        ax[4]=f2bfs(xb2.x); ax[5]=f2bfs(xb2.y); ax[6]=f2bfs(xb2.z); ax[7]=f2bfs(xb2.w);
      }
      const int k2 = kk + 16;
      af = __builtin_amdgcn_mfma_f32_16x16x32_bf16(ax, *(const bf16x8*)(w0 + k2 * 512), af, 0, 0, 0);
      ai = __builtin_amdgcn_mfma_f32_16x16x32_bf16(ax, *(const bf16x8*)(w1 + k2 * 512), ai, 0, 0, 0);
      ac = __builtin_amdgcn_mfma_f32_16x16x32_bf16(ax, *(const bf16x8*)(w2 + k2 * 512), ac, 0, 0, 0);
      ao = __builtin_amdgcn_mfma_f32_16x16x32_bf16(ax, *(const bf16x8*)(w3 + k2 * 512), ao, 0, 0, 0);
    }

    // ---- handoff wait: wave0 only; lane i polls its private flag line ----
    if (wv == 0) {
      const unsigned tgt = (unsigned)t;
      const unsigned int* fp = flg + (lane & 31) * FSTR;
      int guard = 0;
      for (;;) {
        unsigned f;
        asm volatile("global_load_dword %0, %1, off sc0 sc1\n\ts_waitcnt vmcnt(0)"
                     : "=v"(f) : "v"(fp) : "memory");
        if (__all((int)(f >= tgt))) break;
        if (++guard > (1 << 22)) break;
        __builtin_amdgcn_s_sleep(2);
      }
    }
    __syncthreads();
    asm volatile("" ::: "memory");

    // ---- h loads (agent-coherent u64 = L3-fresh) + h half of GEMM ----
    const unsigned long long* hq = (t & 1) ? h1q : h0q;
    #pragma unroll
    for (int kk = 0; kk < 16; ++kk) {
      unsigned long long q0 = __hip_atomic_load(hq + aq + kk * 8,     __ATOMIC_RELAXED, __HIP_MEMORY_SCOPE_AGENT);
      unsigned long long q1 = __hip_atomic_load(hq + aq + kk * 8 + 1, __ATOMIC_RELAXED, __HIP_MEMORY_SCOPE_AGENT);
      union { unsigned long long q[2]; bf16x8 v; } u;
      u.q[0] = q0; u.q[1] = q1;
      bf16x8 ah = u.v;
      af = __builtin_amdgcn_mfma_f32_16x16x32_bf16(ah, *(const bf16x8*)(w0 + kk * 512), af, 0, 0, 0);
      ai = __builtin_amdgcn_mfma_f32_16x16x32_bf16(ah, *(const bf16x8*)(w1 + kk * 512), ai, 0, 0, 0);
      ac = __builtin_amdgcn_mfma_f32_16x16x32_bf16(ah, *(const bf16x8*)(w2 + kk * 512), ac, 0, 0, 0);
      ao = __builtin_amdgcn_mfma_f32_16x16x32_bf16(ah, *(const bf16x8*)(w3 + kk * 512), ao, 0, 0, 0);
    }

    // ---- gates + state update; publish h with PLAIN cached stores ----
    unsigned short* hw = (t & 1) ? hbf0 : hbf1;
    unsigned short hbv[4];
    float hvf[4], cvf[4];
    #pragma unroll
    for (int i2 = 0; i2 < 4; ++i2) {
      float fg = sigmoid_f(af[i2]);
      float ig = sigmoid_f(ai[i2]);
      float gg2 = tanh_f(ac[i2]);
      float og = sigmoid_f(ao[i2]);
      float cN = (i2 == 0) ? c0 : (i2 == 1) ? c1 : (i2 == 2) ? c2 : c3;
      cN = fg * cN + ig * gg2;
      float hv = og * tanh_f(cN);
      if (i2 == 0) c0 = cN; else if (i2 == 1) c1 = cN; else if (i2 == 2) c2 = cN; else c3 = cN;
      hvf[i2] = hv; cvf[i2] = cN;
      unsigned short hb = (unsigned short)f2bfs(hv);
      hbv[i2] = hb;
      hw[(long)(b_cd0 + i2) * H_ + jcol] = hb;      // plain store -> own L2
    }

    // ---- all h stores in L2 (barrier implies vmcnt) -> eager writeback ----
    __syncthreads();
    asm volatile("" ::: "memory");
    if (wv == 0) {
      asm volatile("buffer_wbl2 sc1" ::: "memory");           // L2 -> L3 flush
      asm volatile("s_waitcnt vmcnt(0)" ::: "memory");        // flush complete
      if (lane == 0) {
        (void)__hip_atomic_exchange(flg + jb * FSTR, (unsigned)(t + 1),
                                    __ATOMIC_RELAXED, __HIP_MEMORY_SCOPE_AGENT);
      }
    }

    // ---- off-critical-path: history, tail, next-x prefetch ----
    #pragma unroll
    for (int i2 = 0; i2 < 4; ++i2) {
      int brow = b_cd0 + i2;
      __builtin_nontemporal_store(hbv[i2], hs + ((long)t * B_ + brow) * H_ + jcol);
      if (t == T_ - 1) {
        tail[(long)brow * H_ + jcol] = hvf[i2];
        tail[(long)B_ * H_ + (long)brow * H_ + jcol] = cvf[i2];
      }
    }
    const long tn = (t + 1 < T_) ? (t + 1) : t;
    if constexpr (X16) {
      const unsigned short* xt = xrow16 + tn * D_;
      #pragma unroll
      for (int kk = 0; kk < 16; ++kk) xf[kk] = *(const bf16x8*)(xt + kk * 32);
    } else {
      const float* xt = xrow32 + tn * D_;
      #pragma unroll
      for (int kk = 0; kk < 16; ++kk) {
        xr[2*kk]   = *(const float4*)(xt + kk * 32);
        xr[2*kk+1] = *(const float4*)(xt + kk * 32 + 4);
      }
    }
  }
}

// ---------------------------------------------------------------------------
// Output projection: out(B,T,O) = hs(T,B,H) @ W_hy + b_hy.
// ---------------------------------------------------------------------------
__global__ __launch_bounds__(512) void out_proj(
    const unsigned short* __restrict__ hs,
    const unsigned short* __restrict__ Whyp,
    const float* __restrict__ bhy,
    float* __restrict__ out)
{
  const int tid  = threadIdx.x;
  const int wv   = tid >> 6;
  const int lane = tid & 63;
  const int lrow = lane & 15;
  const int lkg  = lane >> 4;
  const int mg = wv >> 2;
  const int ng = wv & 3;
  const long mbase = (long)blockIdx.x * 128 + mg * 64;

  f32x4 acc[4][8];
  #pragma unroll
  for (int mt = 0; mt < 4; ++mt)
    #pragma unroll
    for (int nt = 0; nt < 8; ++nt) {
      float b = bhy[ng * 128 + nt * 16 + lrow];
      acc[mt][nt] = {b, b, b, b};
    }

  const unsigned short* arow = hs + (mbase + lrow) * 512 + lkg * 8;
  const unsigned short* bbas = Whyp + (long)(ng * 8) * 8192 + lane * 8;

  #pragma unroll
  for (int kk = 0; kk < 16; ++kk) {
    bf16x8 a0 = *(const bf16x8*)(arow + 0 * 8192 + kk * 32);
    bf16x8 a1 = *(const bf16x8*)(arow + 1 * 8192 + kk * 32);
    bf16x8 a2 = *(const bf16x8*)(arow + 2 * 8192 + kk * 32);
    bf16x8 a3 = *(const bf16x8*)(arow + 3 * 8192 + kk * 32);
    #pragma unroll
    for (int nt = 0; nt < 8; ++nt) {
      bf16x8 bv = *(const bf16x8*)(bbas + nt * 8192 + kk * 512);
      acc[0][nt] = __builtin_amdgcn_mfma_f32_16x16x32_bf16(a0, bv, acc[0][nt], 0, 0, 0);
      acc[1][nt] = __builtin_amdgcn_mfma_f32_16x16x32_bf16(a1, bv, acc[1][nt], 0, 0, 0);
      acc[2][nt] = __builtin_amdgcn_mfma_f32_16x16x32_bf16(a2, bv, acc[2][nt], 0, 0, 0);
      acc[3][nt] = __builtin_amdgcn_mfma_f32_16x16x32_bf16(a3, bv, acc[3][nt], 0, 0, 0);
    }
  }

  #pragma unroll
  for (int mt = 0; mt < 4; ++mt) {
    #pragma unroll
    for (int i2 = 0; i2 < 4; ++i2) {
      long m = mbase + mt * 16 + lkg * 4 + i2;
      long t = m >> 6, b = m & 63;
      float* orow = out + (b * 1024 + t) * 512;
      #pragma unroll
      for (int nt = 0; nt < 8; ++nt)
        orow[ng * 128 + nt * 16 + lrow] = acc[mt][nt][i2];
    }
  }
}

// ---------------------------------------------------------------------------
extern "C" void kernel_launch(void* const* d_in, const int* in_sizes, int n_in,
                              void* d_out, int out_size, void* d_ws, size_t ws_size,
                              hipStream_t stream) {
  const float* x      = (const float*)d_in[0];
  const float* h_init = (const float*)d_in[1];
  const float* c_init = (const float*)d_in[2];
  const float* W_f = (const float*)d_in[3];
  const float* b_f = (const float*)d_in[4];
  const float* W_i = (const float*)d_in[5];
  const float* b_i = (const float*)d_in[6];
  const float* W_c = (const float*)d_in[7];
  const float* b_c = (const float*)d_in[8];
  const float* W_o = (const float*)d_in[9];
  const float* b_o = (const float*)d_in[10];
  const float* W_hy = (const float*)d_in[11];
  const float* b_hy = (const float*)d_in[12];
  float* out = (float*)d_out;

  // ws layout (bytes)
  const size_t WP_OFF   = 0;                          // 4 MB
  const size_t WHYP_OFF = 4u << 20;                   // 512 KB
  const size_t HBF0_OFF = WHYP_OFF + (512u << 10);    // 64 KB
  const size_t HBF1_OFF = HBF0_OFF + (64u << 10);     // 64 KB
  const size_t FLG_OFF  = HBF1_OFF + (64u << 10);     // 4 KB strided flags
  const size_t XB_OFF   = 8u << 20;                   // 64 MB (big path only)
  const size_t HS_BYTES = (size_t)T_ * B_ * H_ * 2;   // 64 MB
  const size_t XB_BYTES = (size_t)B_ * T_ * D_ * 2;   // 64 MB
  const size_t NEED_SMALL = (8u << 20) + HS_BYTES;
  const size_t NEED_BIG   = XB_OFF + XB_BYTES + HS_BYTES;
  if (ws_size < NEED_SMALL) return;
  const bool big = (ws_size >= NEED_BIG);

  unsigned char* w = (unsigned char*)d_ws;
  unsigned short* Wp   = (unsigned short*)(w + WP_OFF);
  unsigned short* Whyp = (unsigned short*)(w + WHYP_OFF);
  unsigned short* hbf0 = (unsigned short*)(w + HBF0_OFF);
  unsigned short* hbf1 = (unsigned short*)(w + HBF1_OFF);
  unsigned int*   flg  = (unsigned int*)(w + FLG_OFF);
  unsigned short* xb   = (unsigned short*)(w + XB_OFF);
  unsigned short* hs   = (unsigned short*)(w + (big ? XB_OFF + XB_BYTES : (size_t)(8u << 20)));

  // 1) pack weights + init + flag zeroing
  const long total = 1024L * 2048 + 512L * 512 + 64L * 512;
  int pgrid = (int)((total + 255) / 256);
  pack_setup<<<pgrid, 256, 0, stream>>>(W_f, W_i, W_c, W_o, W_hy, h_init,
                                        Wp, Whyp, hbf0, flg);

  // 2) optional x -> bf16 preconversion
  if (big) {
    const long nx = (long)B_ * T_ * D_;
    int xgrid = (int)(nx / (256 * 8));
    xconv<<<xgrid, 256, 0, stream>>>(x, xb);
  }

  // 3) sequential recurrence (eager-writeback publish)
  float* tail = out + (size_t)B_ * T_ * O_;
  if (big) {
    lstm_seq<true><<<NBLK, 256, 0, stream>>>(xb, c_init, b_f, b_i, b_c, b_o,
                                             Wp, hbf0, hbf1, hs, tail, flg);
  } else {
    lstm_seq<false><<<NBLK, 256, 0, stream>>>(x, c_init, b_f, b_i, b_c, b_o,
                                              Wp, hbf0, hbf1, hs, tail, flg);
  }

  // 4) output projection
  out_proj<<<512, 512, 0, stream>>>(hs, Whyp, b_hy, out);
}